// Round 10
// baseline (4247.996 us; speedup 1.0000x reference)
//
#include <hip/hip_runtime.h>
#include <hip/hip_bf16.h>

#define N_NODES 50000
#define N_EDGES 800000
#define EP (N_EDGES + N_NODES)   // 850000 edges incl. self-loops (appended at end)
#define F_IN 128
#define DH 64
#define HD 256                   // 4 heads * 64
#define NG 32
#define NC 3

// monotone float<->uint mapping for atomicMax on floats
__device__ inline unsigned fenc(float f) {
  unsigned b = __float_as_uint(f);
  return (b & 0x80000000u) ? ~b : (b | 0x80000000u);
}
__device__ inline float fdec(unsigned u) {
  unsigned b = (u & 0x80000000u) ? (u & 0x7fffffffu) : ~u;
  return __uint_as_float(b);
}

// EDGE BUFFER: (2,E) int32 rows, C-order flat = [src_row | dst_row]  (reading A,
// used by R3/R4/R5 whose logits were retroactively validated once the fp32
// output encoding was discovered). Self-loops appended at e >= E.
__device__ inline int src_of(const int* __restrict__ ei, int e) {
  int s = (e < N_EDGES) ? ei[e] : (e - N_EDGES);
  if ((unsigned)s >= N_NODES) s = 0;
  return s;
}
__device__ inline int dst_of(const int* __restrict__ ei, int e) {
  int d = (e < N_EDGES) ? ei[N_EDGES + e] : (e - N_EDGES);
  if ((unsigned)d >= N_NODES) d = 0;
  return d;
}

// ---- naive GEMM: one block per row, one thread per col (fp32)
__global__ void k_gemm_naive(const float* __restrict__ A, const float* __restrict__ W,
                             float* __restrict__ C, int K, int Nn) {
  int row = blockIdx.x;
  int col = threadIdx.x;           // blockDim.x == Nn
  float acc = 0.f;
  for (int k = 0; k < K; ++k)
    acc += A[(size_t)row * K + k] * W[(size_t)k * Nn + col];
  C[(size_t)row * Nn + col] = acc;
}

// ---- per-(node,head) attention logits
__global__ void k_node_scores(const float* __restrict__ h,
                              const float* __restrict__ a_s,
                              const float* __restrict__ a_d,
                              float* __restrict__ al_s, float* __restrict__ al_d,
                              int heads, int hd) {
  int idx = blockIdx.x * blockDim.x + threadIdx.x;
  if (idx >= N_NODES * heads) return;
  int n = idx / heads, hh = idx % heads;
  float ps = 0.f, pd = 0.f;
  for (int d = 0; d < DH; ++d) {
    float v = h[(size_t)n * hd + hh * DH + d];
    ps += v * a_s[hh * DH + d];
    pd += v * a_d[hh * DH + d];
  }
  al_s[idx] = ps;
  al_d[idx] = pd;
}

// ---- edge scores: leaky_relu(al_s[src] + al_d[dst])
__global__ void k_edge_scores(const int* __restrict__ ei,
                              const float* __restrict__ al_s,
                              const float* __restrict__ al_d,
                              float* __restrict__ sc, int heads) {
  int e = blockIdx.x * blockDim.x + threadIdx.x;
  if (e >= EP) return;
  int s = src_of(ei, e), d = dst_of(ei, e);
  for (int hh = 0; hh < heads; ++hh) {
    float v = al_s[s * heads + hh] + al_d[d * heads + hh];
    v = v > 0.f ? v : 0.2f * v;
    v = (v == v) ? v : 0.f;
    sc[(size_t)e * heads + hh] = v;
  }
}

__global__ void k_fill_neginf(unsigned* __restrict__ umax, int n) {
  int i = blockIdx.x * blockDim.x + threadIdx.x;
  if (i < n) umax[i] = fenc(-3.4e38f);
}

// ---- segment max via atomicMax (monotone uint encoding)
__global__ void k_smax(const int* __restrict__ ei, const float* __restrict__ sc,
                       unsigned* __restrict__ umax, int heads) {
  int idx = blockIdx.x * blockDim.x + threadIdx.x;
  if (idx >= EP * heads) return;
  int e = idx / heads, hh = idx % heads;
  int d = dst_of(ei, e);
  atomicMax(&umax[d * heads + hh], fenc(sc[idx]));
}

// ---- segment sum of exp(sc - m)
__global__ void k_ssum(const int* __restrict__ ei, const float* __restrict__ sc,
                       const unsigned* __restrict__ umax, float* __restrict__ ssum,
                       int heads) {
  int idx = blockIdx.x * blockDim.x + threadIdx.x;
  if (idx >= EP * heads) return;
  int e = idx / heads, hh = idx % heads;
  int d = dst_of(ei, e);
  float m = fdec(umax[d * heads + hh]);
  atomicAdd(&ssum[d * heads + hh], __expf(sc[idx] - m));
}

__global__ void k_rinv(float* __restrict__ ssum, int n) {
  int i = blockIdx.x * blockDim.x + threadIdx.x;
  if (i >= n) return;
  float s = ssum[i];
  ssum[i] = (s > 0.f) ? 1.f / s : 0.f;
}

// ---- alpha -> att output (fp32), original edge order
__global__ void k_alpha(const int* __restrict__ ei, const float* __restrict__ sc,
                        const unsigned* __restrict__ umax, const float* __restrict__ rinv,
                        float* __restrict__ att, int heads) {
  int idx = blockIdx.x * blockDim.x + threadIdx.x;
  if (idx >= EP * heads) return;
  int e = idx / heads, hh = idx % heads;
  int d = dst_of(ei, e);
  float m = fdec(umax[d * heads + hh]);
  att[idx] = __expf(sc[idx] - m) * rinv[d * heads + hh];
}

// ---- message scatter-add: one block per edge, thread = feature
__global__ void k_msg(const int* __restrict__ ei, const float* __restrict__ sc,
                      const unsigned* __restrict__ umax, const float* __restrict__ rinv,
                      const float* __restrict__ h, float* __restrict__ out_acc,
                      int heads, int hd) {
  int e = blockIdx.x;
  int f = threadIdx.x;             // blockDim.x == hd
  int s = src_of(ei, e), d = dst_of(ei, e);
  int hh = f >> 6;                 // f / DH
  float m = fdec(umax[d * heads + hh]);
  float al = __expf(sc[(size_t)e * heads + hh] - m) * rinv[d * heads + hh];
  atomicAdd(&out_acc[(size_t)d * hd + f], al * h[(size_t)s * hd + f]);
}

// ---- bias + ELU, in place (fp32)
__global__ void k_bias_elu(float* __restrict__ acc, const float* __restrict__ b,
                           int total, int hd) {
  int i = blockIdx.x * blockDim.x + threadIdx.x;
  if (i >= total) return;
  float v = acc[i] + b[i % hd];
  acc[i] = v > 0.f ? v : expm1f(v);
}

// ---- layer-3 bias + segment-sum pooling
__global__ void k_pool(const float* __restrict__ acc, const float* __restrict__ b3,
                       const int* __restrict__ batch,
                       float* __restrict__ pooled, float* __restrict__ cnt) {
  int i = blockIdx.x * blockDim.x + threadIdx.x;
  if (i >= N_NODES * DH) return;
  int n = i / DH, d = i % DH;
  float v = acc[i] + b3[d];
  int g = batch[n] & (NG - 1);
  atomicAdd(&pooled[g * DH + d], v);
  if (d == 0) atomicAdd(&cnt[g], 1.f);
}

// ---- final tiny MLP (one block), fp32 logits
__global__ void k_mlp(const float* __restrict__ pooled, const float* __restrict__ cnt,
                      const float* __restrict__ Wc1, const float* __restrict__ bc1,
                      const float* __restrict__ Wc2, const float* __restrict__ bc2,
                      float* __restrict__ out) {
  __shared__ float hid[NG * 32];
  int t = threadIdx.x;
  for (int idx = t; idx < NG * 32; idx += blockDim.x) {
    int g = idx / 32, j = idx % 32;
    float invc = 1.f / fmaxf(cnt[g], 1.f);
    float a = bc1[j];
    for (int d = 0; d < DH; ++d)
      a += pooled[g * DH + d] * invc * Wc1[d * 32 + j];
    hid[idx] = a > 0.f ? a : 0.f;
  }
  __syncthreads();
  for (int idx = t; idx < NG * NC; idx += blockDim.x) {
    int g = idx / NC, c = idx % NC;
    float a = bc2[c];
    for (int j = 0; j < 32; ++j)
      a += hid[g * 32 + j] * Wc2[j * NC + c];
    out[idx] = a;
  }
}

extern "C" void kernel_launch(void* const* d_in, const int* in_sizes, int n_in,
                              void* d_out, int out_size, void* d_ws, size_t ws_size,
                              hipStream_t stream) {
  const float* x   = (const float*)d_in[0];
  const int* ei    = (const int*)d_in[1];     // (2,E) rows, int32
  const int* batch = (const int*)d_in[2];
  const float* W1  = (const float*)d_in[3];
  const float* as1 = (const float*)d_in[4];
  const float* ad1 = (const float*)d_in[5];
  const float* b1  = (const float*)d_in[6];
  const float* W2  = (const float*)d_in[7];
  const float* as2 = (const float*)d_in[8];
  const float* ad2 = (const float*)d_in[9];
  const float* b2  = (const float*)d_in[10];
  const float* W3  = (const float*)d_in[11];
  const float* as3 = (const float*)d_in[12];
  const float* ad3 = (const float*)d_in[13];
  const float* b3  = (const float*)d_in[14];
  const float* Wc1 = (const float*)d_in[15];
  const float* bc1 = (const float*)d_in[16];
  const float* Wc2 = (const float*)d_in[17];
  const float* bc2 = (const float*)d_in[18];
  float* out = (float*)d_out;                 // fp32 outputs (diagnosed R9)

  // workspace carve (~120 MB)
  char* w = (char*)d_ws;
  float*    h_f32   = (float*)(w + 0);            // 51,200,000
  float*    out_acc = (float*)(w + 51200000);     // 51,200,000 (x2/x3 after in-place ELU)
  float*    al_s    = (float*)(w + 102400000);    // 800,000
  float*    al_d    = (float*)(w + 103200000);    // 800,000
  float*    sc      = (float*)(w + 104000000);    // 13,600,000
  unsigned* umax    = (unsigned*)(w + 117600000); // 800,000
  float*    ssum    = (float*)(w + 118400000);    // 800,000
  float*    pooled  = (float*)(w + 119200000);    // 8,192
  float*    gcnt    = (float*)(w + 119208192);    // 128

  const int EB  = (EP + 255) / 256;
  const int EH4 = (EP * 4 + 255) / 256;
  const int NH4 = (N_NODES * 4 + 255) / 256;

  hipMemsetAsync(pooled, 0, NG * DH * sizeof(float), stream);
  hipMemsetAsync(gcnt, 0, NG * sizeof(float), stream);

  float* att1 = out + 96;
  float* att2 = out + 3400096;
  float* att3 = out + 6800096;

  // ================= layer 1: x[N,128] @ W1[128,256] =================
  k_gemm_naive<<<N_NODES, HD, 0, stream>>>(x, W1, h_f32, F_IN, HD);
  k_node_scores<<<NH4, 256, 0, stream>>>(h_f32, as1, ad1, al_s, al_d, 4, HD);
  k_edge_scores<<<EB, 256, 0, stream>>>(ei, al_s, al_d, sc, 4);
  k_fill_neginf<<<NH4, 256, 0, stream>>>(umax, N_NODES * 4);
  k_smax<<<EH4, 256, 0, stream>>>(ei, sc, umax, 4);
  hipMemsetAsync(ssum, 0, N_NODES * 4 * sizeof(float), stream);
  k_ssum<<<EH4, 256, 0, stream>>>(ei, sc, umax, ssum, 4);
  k_rinv<<<NH4, 256, 0, stream>>>(ssum, N_NODES * 4);
  k_alpha<<<EH4, 256, 0, stream>>>(ei, sc, umax, ssum, att1, 4);
  hipMemsetAsync(out_acc, 0, (size_t)N_NODES * HD * sizeof(float), stream);
  k_msg<<<EP, HD, 0, stream>>>(ei, sc, umax, ssum, h_f32, out_acc, 4, HD);
  k_bias_elu<<<(N_NODES * HD + 255) / 256, 256, 0, stream>>>(out_acc, b1, N_NODES * HD, HD);

  // ================= layer 2: x2[N,256] @ W2[256,256] =================
  k_gemm_naive<<<N_NODES, HD, 0, stream>>>(out_acc, W2, h_f32, HD, HD);
  k_node_scores<<<NH4, 256, 0, stream>>>(h_f32, as2, ad2, al_s, al_d, 4, HD);
  k_edge_scores<<<EB, 256, 0, stream>>>(ei, al_s, al_d, sc, 4);
  k_fill_neginf<<<NH4, 256, 0, stream>>>(umax, N_NODES * 4);
  k_smax<<<EH4, 256, 0, stream>>>(ei, sc, umax, 4);
  hipMemsetAsync(ssum, 0, N_NODES * 4 * sizeof(float), stream);
  k_ssum<<<EH4, 256, 0, stream>>>(ei, sc, umax, ssum, 4);
  k_rinv<<<NH4, 256, 0, stream>>>(ssum, N_NODES * 4);
  k_alpha<<<EH4, 256, 0, stream>>>(ei, sc, umax, ssum, att2, 4);
  hipMemsetAsync(out_acc, 0, (size_t)N_NODES * HD * sizeof(float), stream);
  k_msg<<<EP, HD, 0, stream>>>(ei, sc, umax, ssum, h_f32, out_acc, 4, HD);
  k_bias_elu<<<(N_NODES * HD + 255) / 256, 256, 0, stream>>>(out_acc, b2, N_NODES * HD, HD);

  // ================= layer 3: x3[N,256] @ W3[256,64], heads=1 =================
  k_gemm_naive<<<N_NODES, DH, 0, stream>>>(out_acc, W3, h_f32, HD, DH);
  k_node_scores<<<(N_NODES + 255) / 256, 256, 0, stream>>>(h_f32, as3, ad3, al_s, al_d, 1, DH);
  k_edge_scores<<<EB, 256, 0, stream>>>(ei, al_s, al_d, sc, 1);
  k_fill_neginf<<<(N_NODES + 255) / 256, 256, 0, stream>>>(umax, N_NODES);
  k_smax<<<EB, 256, 0, stream>>>(ei, sc, umax, 1);
  hipMemsetAsync(ssum, 0, N_NODES * sizeof(float), stream);
  k_ssum<<<EB, 256, 0, stream>>>(ei, sc, umax, ssum, 1);
  k_rinv<<<(N_NODES + 255) / 256, 256, 0, stream>>>(ssum, N_NODES);
  k_alpha<<<EB, 256, 0, stream>>>(ei, sc, umax, ssum, att3, 1);
  hipMemsetAsync(out_acc, 0, (size_t)N_NODES * DH * sizeof(float), stream);
  k_msg<<<EP, DH, 0, stream>>>(ei, sc, umax, ssum, h_f32, out_acc, 1, DH);

  // ---- pooling + classifier head
  k_pool<<<(N_NODES * DH + 255) / 256, 256, 0, stream>>>(out_acc, b3, batch, pooled, gcnt);
  k_mlp<<<1, 256, 0, stream>>>(pooled, gcnt, Wc1, bc1, Wc2, bc2, out);
}

// Round 11
// 2229.000 us; speedup vs baseline: 1.9058x; 1.9058x over previous
//
#include <hip/hip_runtime.h>
#include <hip/hip_bf16.h>

#define N_NODES 50000
#define N_EDGES 800000
#define EP (N_EDGES + N_NODES)   // 850000 edges incl. self-loops (appended at end)
#define F_IN 128
#define DH 64
#define HD 256                   // 4 heads * 64
#define NG 32
#define NC 3
#define SCB 782                  // ceil(N_NODES/64)

__device__ inline float wave_max(float v) {
#pragma unroll
  for (int o = 32; o > 0; o >>= 1) v = fmaxf(v, __shfl_xor(v, o));
  return v;
}
__device__ inline float wave_sum(float v) {
#pragma unroll
  for (int o = 32; o > 0; o >>= 1) v += __shfl_xor(v, o);
  return v;
}
__device__ inline int wave_isum(int v) {
#pragma unroll
  for (int o = 32; o > 0; o >>= 1) v += __shfl_xor(v, o);
  return v;
}
__device__ inline int wave_iscan(int v, int lane) {   // inclusive
#pragma unroll
  for (int o = 1; o < 64; o <<= 1) {
    int t = __shfl_up(v, o);
    if (lane >= o) v += t;
  }
  return v;
}

// EDGE BUFFER: (2,E) int32 rows. src=ei[e], dst=ei[E+e]; self-loops at e>=E.
__device__ inline int src_of(const int* __restrict__ ei, int e) {
  int s = (e < N_EDGES) ? ei[e] : (e - N_EDGES);
  if ((unsigned)s >= N_NODES) s = 0;
  return s;
}
__device__ inline int dst_of(const int* __restrict__ ei, int e) {
  int d = (e < N_EDGES) ? ei[N_EDGES + e] : (e - N_EDGES);
  if ((unsigned)d >= N_NODES) d = 0;
  return d;
}

// ---- tiled fp32 GEMM: C[M,Nn] = A[M,K] @ W[K,Nn]; 64x64 tile, 4x4 per thread
#define BM 64
#define BN 64
#define BK 32
__global__ __launch_bounds__(256) void k_gemm(const float* __restrict__ A,
                                              const float* __restrict__ W,
                                              float* __restrict__ C,
                                              int M, int Nn, int K) {
  __shared__ float As[BK][BM + 1];
  __shared__ float Ws[BK][BN + 1];
  int t = threadIdx.x;
  int bm0 = blockIdx.y * BM, bn0 = blockIdx.x * BN;
  int ar = t >> 2, ak = (t & 3) * 8;      // A: 64 rows x 32 k, 8 floats/thread
  int wk = t >> 3, wc = (t & 7) * 8;      // W: 32 k x 64 cols, 8 floats/thread
  int ty = t >> 4, tx = t & 15;
  float acc[4][4] = {{0.f}};
  for (int k0 = 0; k0 < K; k0 += BK) {
    int arow = bm0 + ar;
    if (arow < M) {
      const float* ap = A + (size_t)arow * K + k0 + ak;
      float4 a0 = *(const float4*)ap;
      float4 a1 = *(const float4*)(ap + 4);
      As[ak + 0][ar] = a0.x; As[ak + 1][ar] = a0.y;
      As[ak + 2][ar] = a0.z; As[ak + 3][ar] = a0.w;
      As[ak + 4][ar] = a1.x; As[ak + 5][ar] = a1.y;
      As[ak + 6][ar] = a1.z; As[ak + 7][ar] = a1.w;
    } else {
#pragma unroll
      for (int j = 0; j < 8; ++j) As[ak + j][ar] = 0.f;
    }
    {
      const float* wp = W + (size_t)(k0 + wk) * Nn + bn0 + wc;
      float4 w0 = *(const float4*)wp;
      float4 w1 = *(const float4*)(wp + 4);
      Ws[wk][wc + 0] = w0.x; Ws[wk][wc + 1] = w0.y;
      Ws[wk][wc + 2] = w0.z; Ws[wk][wc + 3] = w0.w;
      Ws[wk][wc + 4] = w1.x; Ws[wk][wc + 5] = w1.y;
      Ws[wk][wc + 6] = w1.z; Ws[wk][wc + 7] = w1.w;
    }
    __syncthreads();
#pragma unroll
    for (int kk = 0; kk < BK; ++kk) {
      float ra[4], rb[4];
#pragma unroll
      for (int i = 0; i < 4; ++i) ra[i] = As[kk][ty * 4 + i];
#pragma unroll
      for (int j = 0; j < 4; ++j) rb[j] = Ws[kk][tx * 4 + j];
#pragma unroll
      for (int i = 0; i < 4; ++i)
#pragma unroll
        for (int j = 0; j < 4; ++j) acc[i][j] += ra[i] * rb[j];
    }
    __syncthreads();
  }
#pragma unroll
  for (int i = 0; i < 4; ++i) {
    int row = bm0 + ty * 4 + i;
    if (row >= M) continue;
#pragma unroll
    for (int j = 0; j < 4; ++j)
      C[(size_t)row * Nn + bn0 + tx * 4 + j] = acc[i][j];
  }
}

// ---- per-(node,head) attention logits
__global__ void k_node_scores(const float* __restrict__ h,
                              const float* __restrict__ a_s,
                              const float* __restrict__ a_d,
                              float* __restrict__ al_s, float* __restrict__ al_d,
                              int heads, int hd) {
  int idx = blockIdx.x * blockDim.x + threadIdx.x;
  if (idx >= N_NODES * heads) return;
  int n = idx / heads, hh = idx % heads;
  float ps = 0.f, pd = 0.f;
  for (int d = 0; d < DH; ++d) {
    float v = h[(size_t)n * hd + hh * DH + d];
    ps += v * a_s[hh * DH + d];
    pd += v * a_d[hh * DH + d];
  }
  al_s[idx] = ps;
  al_d[idx] = pd;
}

// ---- edge scores: leaky_relu(al_s[src] + al_d[dst])
__global__ void k_edge_scores(const int* __restrict__ ei,
                              const float* __restrict__ al_s,
                              const float* __restrict__ al_d,
                              float* __restrict__ sc, int heads) {
  int e = blockIdx.x * blockDim.x + threadIdx.x;
  if (e >= EP) return;
  int s = src_of(ei, e), d = dst_of(ei, e);
  for (int hh = 0; hh < heads; ++hh) {
    float v = al_s[s * heads + hh] + al_d[d * heads + hh];
    v = v > 0.f ? v : 0.2f * v;
    v = (v == v) ? v : 0.f;
    sc[(size_t)e * heads + hh] = v;
  }
}

// ---- CSR build (by dst): count / 3-stage wave scan / scatter  [validated R3==R5]
__global__ void k_count(const int* __restrict__ ei, int* __restrict__ counts) {
  int e = blockIdx.x * blockDim.x + threadIdx.x;
  if (e >= EP) return;
  atomicAdd(&counts[dst_of(ei, e)], 1);
}
__global__ void k_scan_a(const int* __restrict__ counts, int* __restrict__ part) {
  int lane = threadIdx.x;
  int i = blockIdx.x * 64 + lane;
  int v = (i < N_NODES) ? counts[i] : 0;
  v = wave_isum(v);
  if (lane == 0) part[blockIdx.x] = v;
}
__global__ void k_scan_b(const int* __restrict__ part, int* __restrict__ partpref) {
  int lane = threadIdx.x;
  int carry = 0;
  for (int base = 0; base < SCB; base += 64) {
    int i = base + lane;
    int v = (i < SCB) ? part[i] : 0;
    int inc = wave_iscan(v, lane);
    if (i < SCB) partpref[i] = carry + inc - v;
    carry += __shfl(inc, 63);
  }
  if (lane == 0) partpref[SCB] = carry;
}
__global__ void k_scan_c(const int* __restrict__ counts, const int* __restrict__ partpref,
                         int* __restrict__ row_ptr, int* __restrict__ cursor) {
  int b = blockIdx.x, lane = threadIdx.x;
  int i = b * 64 + lane;
  int v = (i < N_NODES) ? counts[i] : 0;
  int inc = wave_iscan(v, lane);
  int excl = partpref[b] + inc - v;
  if (i < N_NODES) { row_ptr[i] = excl; cursor[i] = excl; }
  if (i == N_NODES - 1) row_ptr[N_NODES] = excl + v;
}
__global__ void k_scatter(const int* __restrict__ ei, int* __restrict__ cursor,
                          int* __restrict__ eidx) {
  int e = blockIdx.x * blockDim.x + threadIdx.x;
  if (e >= EP) return;
  int pos = atomicAdd(&cursor[dst_of(ei, e)], 1);
  if ((unsigned)pos < EP) eidx[pos] = e;
}

// ---- per-(dst,head) wave: softmax over in-edges + weighted gather-sum + alpha store
__global__ void k_aggregate(const float* __restrict__ sc,
                            const int* __restrict__ eidx,
                            const int* __restrict__ row_ptr,
                            const int* __restrict__ ei,
                            const float* __restrict__ h,
                            float* __restrict__ out_acc,
                            float* __restrict__ att,
                            int heads, int hd) {
  int wid = blockIdx.x * (blockDim.x >> 6) + (threadIdx.x >> 6);
  if (wid >= N_NODES * heads) return;
  int lane = threadIdx.x & 63;
  int n = wid / heads, hh = wid % heads;
  int beg = row_ptr[n], end = row_ptr[n + 1];
  if (beg < 0) beg = 0;
  if (end > EP) end = EP;
  float m = -1e30f;
  for (int i = beg + lane; i < end; i += 64) {
    unsigned ue = (unsigned)eidx[i];
    int eid = (ue < EP) ? (int)ue : 0;
    m = fmaxf(m, sc[(size_t)eid * heads + hh]);
  }
  m = wave_max(m);
  float ssum = 0.f;
  for (int i = beg + lane; i < end; i += 64) {
    unsigned ue = (unsigned)eidx[i];
    int eid = (ue < EP) ? (int)ue : 0;
    ssum += __expf(sc[(size_t)eid * heads + hh] - m);
  }
  ssum = wave_sum(ssum);
  float inv = (ssum > 0.f) ? 1.f / ssum : 0.f;
  float acc = 0.f;
  for (int i = beg; i < end; ++i) {
    unsigned ue = (unsigned)eidx[i];
    int eid = (ue < EP) ? (int)ue : 0;
    float al = __expf(sc[(size_t)eid * heads + hh] - m) * inv;
    int s = src_of(ei, eid);
    acc += al * h[(size_t)s * hd + hh * DH + lane];
    if (lane == 0) att[(size_t)eid * heads + hh] = al;
  }
  out_acc[(size_t)n * hd + hh * DH + lane] = acc;
}

// ---- bias + ELU, in place (fp32)
__global__ void k_bias_elu(float* __restrict__ acc, const float* __restrict__ b,
                           int total, int hd) {
  int i = blockIdx.x * blockDim.x + threadIdx.x;
  if (i >= total) return;
  float v = acc[i] + b[i % hd];
  acc[i] = v > 0.f ? v : expm1f(v);
}

// ---- layer-3 bias + segment-sum pooling
__global__ void k_pool(const float* __restrict__ acc, const float* __restrict__ b3,
                       const int* __restrict__ batch,
                       float* __restrict__ pooled, float* __restrict__ cnt) {
  int i = blockIdx.x * blockDim.x + threadIdx.x;
  if (i >= N_NODES * DH) return;
  int n = i / DH, d = i % DH;
  float v = acc[i] + b3[d];
  int g = batch[n] & (NG - 1);
  atomicAdd(&pooled[g * DH + d], v);
  if (d == 0) atomicAdd(&cnt[g], 1.f);
}

// ---- final tiny MLP (one block), fp32 logits
__global__ void k_mlp(const float* __restrict__ pooled, const float* __restrict__ cnt,
                      const float* __restrict__ Wc1, const float* __restrict__ bc1,
                      const float* __restrict__ Wc2, const float* __restrict__ bc2,
                      float* __restrict__ out) {
  __shared__ float hid[NG * 32];
  int t = threadIdx.x;
  for (int idx = t; idx < NG * 32; idx += blockDim.x) {
    int g = idx / 32, j = idx % 32;
    float invc = 1.f / fmaxf(cnt[g], 1.f);
    float a = bc1[j];
    for (int d = 0; d < DH; ++d)
      a += pooled[g * DH + d] * invc * Wc1[d * 32 + j];
    hid[idx] = a > 0.f ? a : 0.f;
  }
  __syncthreads();
  for (int idx = t; idx < NG * NC; idx += blockDim.x) {
    int g = idx / NC, c = idx % NC;
    float a = bc2[c];
    for (int j = 0; j < 32; ++j)
      a += hid[g * 32 + j] * Wc2[j * NC + c];
    out[idx] = a;
  }
}

extern "C" void kernel_launch(void* const* d_in, const int* in_sizes, int n_in,
                              void* d_out, int out_size, void* d_ws, size_t ws_size,
                              hipStream_t stream) {
  const float* x   = (const float*)d_in[0];
  const int* ei    = (const int*)d_in[1];     // (2,E) rows, int32
  const int* batch = (const int*)d_in[2];
  const float* W1  = (const float*)d_in[3];
  const float* as1 = (const float*)d_in[4];
  const float* ad1 = (const float*)d_in[5];
  const float* b1  = (const float*)d_in[6];
  const float* W2  = (const float*)d_in[7];
  const float* as2 = (const float*)d_in[8];
  const float* ad2 = (const float*)d_in[9];
  const float* b2  = (const float*)d_in[10];
  const float* W3  = (const float*)d_in[11];
  const float* as3 = (const float*)d_in[12];
  const float* ad3 = (const float*)d_in[13];
  const float* b3  = (const float*)d_in[14];
  const float* Wc1 = (const float*)d_in[15];
  const float* bc1 = (const float*)d_in[16];
  const float* Wc2 = (const float*)d_in[17];
  const float* bc2 = (const float*)d_in[18];
  float* out = (float*)d_out;                 // fp32 outputs

  // workspace carve (~122 MB)
  char* w = (char*)d_ws;
  float* h_f32   = (float*)(w + 0);            // 51,200,000
  float* out_acc = (float*)(w + 51200000);     // 51,200,000 (x2/x3 after in-place ELU)
  float* al_s    = (float*)(w + 102400000);    // 800,000
  float* al_d    = (float*)(w + 103200000);    // 800,000
  float* sc      = (float*)(w + 104000000);    // 13,600,000
  int*   counts  = (int*)(w + 117600000);      // 200,000
  int*   cursor  = (int*)(w + 117800000);      // 200,000
  int*   row_ptr = (int*)(w + 118000000);      // 200,004
  int*   eidx    = (int*)(w + 118200064);      // 3,400,000
  int*   part    = (int*)(w + 121600064);      // 3,200
  int*   partpref= (int*)(w + 121603264);      // 3,200
  float* pooled  = (float*)(w + 121606464);    // 8,192
  float* gcnt    = (float*)(w + 121614656);    // 128

  const int EB  = (EP + 255) / 256;
  const int NH4 = (N_NODES * 4 + 255) / 256;

  hipMemsetAsync(counts, 0, N_NODES * sizeof(int), stream);
  hipMemsetAsync(eidx, 0, EP * sizeof(int), stream);
  hipMemsetAsync(pooled, 0, NG * DH * sizeof(float), stream);
  hipMemsetAsync(gcnt, 0, NG * sizeof(float), stream);

  // ---- CSR build (shared by all 3 layers)
  k_count<<<EB, 256, 0, stream>>>(ei, counts);
  k_scan_a<<<SCB, 64, 0, stream>>>(counts, part);
  k_scan_b<<<1, 64, 0, stream>>>(part, partpref);
  k_scan_c<<<SCB, 64, 0, stream>>>(counts, partpref, row_ptr, cursor);
  k_scatter<<<EB, 256, 0, stream>>>(ei, cursor, eidx);

  float* att1 = out + 96;
  float* att2 = out + 3400096;
  float* att3 = out + 6800096;

  dim3 gh(HD / BN, (N_NODES + BM - 1) / BM);   // 4 x 782
  dim3 gd(DH / BN, (N_NODES + BM - 1) / BM);   // 1 x 782

  // ================= layer 1: x[N,128] @ W1[128,256] =================
  k_gemm<<<gh, 256, 0, stream>>>(x, W1, h_f32, N_NODES, HD, F_IN);
  k_node_scores<<<NH4, 256, 0, stream>>>(h_f32, as1, ad1, al_s, al_d, 4, HD);
  k_edge_scores<<<EB, 256, 0, stream>>>(ei, al_s, al_d, sc, 4);
  k_aggregate<<<N_NODES, 256, 0, stream>>>(sc, eidx, row_ptr, ei, h_f32,
                                           out_acc, att1, 4, HD);
  k_bias_elu<<<(N_NODES * HD + 255) / 256, 256, 0, stream>>>(out_acc, b1, N_NODES * HD, HD);

  // ================= layer 2: x2[N,256] @ W2[256,256] =================
  k_gemm<<<gh, 256, 0, stream>>>(out_acc, W2, h_f32, N_NODES, HD, HD);
  k_node_scores<<<NH4, 256, 0, stream>>>(h_f32, as2, ad2, al_s, al_d, 4, HD);
  k_edge_scores<<<EB, 256, 0, stream>>>(ei, al_s, al_d, sc, 4);
  k_aggregate<<<N_NODES, 256, 0, stream>>>(sc, eidx, row_ptr, ei, h_f32,
                                           out_acc, att2, 4, HD);
  k_bias_elu<<<(N_NODES * HD + 255) / 256, 256, 0, stream>>>(out_acc, b2, N_NODES * HD, HD);

  // ================= layer 3: x3[N,256] @ W3[256,64], heads=1 =================
  k_gemm<<<gd, 256, 0, stream>>>(out_acc, W3, h_f32, N_NODES, DH, HD);
  k_node_scores<<<(N_NODES + 255) / 256, 256, 0, stream>>>(h_f32, as3, ad3, al_s, al_d, 1, DH);
  k_edge_scores<<<EB, 256, 0, stream>>>(ei, al_s, al_d, sc, 1);
  k_aggregate<<<N_NODES / 4, 256, 0, stream>>>(sc, eidx, row_ptr, ei, h_f32,
                                               out_acc, att3, 1, DH);

  // ---- pooling + classifier head
  k_pool<<<(N_NODES * DH + 255) / 256, 256, 0, stream>>>(out_acc, b3, batch, pooled, gcnt);
  k_mlp<<<1, 256, 0, stream>>>(pooled, gcnt, Wc1, bc1, Wc2, bc2, out);
}

// Round 12
// 1740.640 us; speedup vs baseline: 2.4405x; 1.2806x over previous
//
#include <hip/hip_runtime.h>
#include <hip/hip_bf16.h>

#define N_NODES 50000
#define N_EDGES 800000
#define EP (N_EDGES + N_NODES)   // 850000 edges incl. self-loops (appended at end)
#define F_IN 128
#define DH 64
#define HD 256                   // 4 heads * 64
#define NG 32
#define NC 3
#define SCB 782                  // ceil(N_NODES/64)

__device__ inline float wave_max(float v) {
#pragma unroll
  for (int o = 32; o > 0; o >>= 1) v = fmaxf(v, __shfl_xor(v, o));
  return v;
}
__device__ inline float wave_sum(float v) {
#pragma unroll
  for (int o = 32; o > 0; o >>= 1) v += __shfl_xor(v, o);
  return v;
}
__device__ inline int wave_isum(int v) {
#pragma unroll
  for (int o = 32; o > 0; o >>= 1) v += __shfl_xor(v, o);
  return v;
}
__device__ inline int wave_iscan(int v, int lane) {   // inclusive
#pragma unroll
  for (int o = 1; o < 64; o <<= 1) {
    int t = __shfl_up(v, o);
    if (lane >= o) v += t;
  }
  return v;
}

// EDGE BUFFER: (2,E) int32 rows. src=ei[e], dst=ei[E+e]; self-loops at e>=E.
__device__ inline int src_of(const int* __restrict__ ei, int e) {
  int s = (e < N_EDGES) ? ei[e] : (e - N_EDGES);
  if ((unsigned)s >= N_NODES) s = 0;
  return s;
}
__device__ inline int dst_of(const int* __restrict__ ei, int e) {
  int d = (e < N_EDGES) ? ei[N_EDGES + e] : (e - N_EDGES);
  if ((unsigned)d >= N_NODES) d = 0;
  return d;
}

// ---- tiled fp32 GEMM: C[M,Nn] = A[M,K] @ W[K,Nn]; 64x64 tile, 4x4 per thread
#define BM 64
#define BN 64
#define BK 32
__global__ __launch_bounds__(256) void k_gemm(const float* __restrict__ A,
                                              const float* __restrict__ W,
                                              float* __restrict__ C,
                                              int M, int Nn, int K) {
  __shared__ float As[BK][BM + 1];
  __shared__ float Ws[BK][BN + 1];
  int t = threadIdx.x;
  int bm0 = blockIdx.y * BM, bn0 = blockIdx.x * BN;
  int ar = t >> 2, ak = (t & 3) * 8;      // A: 64 rows x 32 k, 8 floats/thread
  int wk = t >> 3, wc = (t & 7) * 8;      // W: 32 k x 64 cols, 8 floats/thread
  int ty = t >> 4, tx = t & 15;
  float acc[4][4] = {{0.f}};
  for (int k0 = 0; k0 < K; k0 += BK) {
    int arow = bm0 + ar;
    if (arow < M) {
      const float* ap = A + (size_t)arow * K + k0 + ak;
      float4 a0 = *(const float4*)ap;
      float4 a1 = *(const float4*)(ap + 4);
      As[ak + 0][ar] = a0.x; As[ak + 1][ar] = a0.y;
      As[ak + 2][ar] = a0.z; As[ak + 3][ar] = a0.w;
      As[ak + 4][ar] = a1.x; As[ak + 5][ar] = a1.y;
      As[ak + 6][ar] = a1.z; As[ak + 7][ar] = a1.w;
    } else {
#pragma unroll
      for (int j = 0; j < 8; ++j) As[ak + j][ar] = 0.f;
    }
    {
      const float* wp = W + (size_t)(k0 + wk) * Nn + bn0 + wc;
      float4 w0 = *(const float4*)wp;
      float4 w1 = *(const float4*)(wp + 4);
      Ws[wk][wc + 0] = w0.x; Ws[wk][wc + 1] = w0.y;
      Ws[wk][wc + 2] = w0.z; Ws[wk][wc + 3] = w0.w;
      Ws[wk][wc + 4] = w1.x; Ws[wk][wc + 5] = w1.y;
      Ws[wk][wc + 6] = w1.z; Ws[wk][wc + 7] = w1.w;
    }
    __syncthreads();
#pragma unroll
    for (int kk = 0; kk < BK; ++kk) {
      float ra[4], rb[4];
#pragma unroll
      for (int i = 0; i < 4; ++i) ra[i] = As[kk][ty * 4 + i];
#pragma unroll
      for (int j = 0; j < 4; ++j) rb[j] = Ws[kk][tx * 4 + j];
#pragma unroll
      for (int i = 0; i < 4; ++i)
#pragma unroll
        for (int j = 0; j < 4; ++j) acc[i][j] += ra[i] * rb[j];
    }
    __syncthreads();
  }
#pragma unroll
  for (int i = 0; i < 4; ++i) {
    int row = bm0 + ty * 4 + i;
    if (row >= M) continue;
#pragma unroll
    for (int j = 0; j < 4; ++j)
      C[(size_t)row * Nn + bn0 + tx * 4 + j] = acc[i][j];
  }
}

// ---- per-(node,head) attention logits
__global__ void k_node_scores(const float* __restrict__ h,
                              const float* __restrict__ a_s,
                              const float* __restrict__ a_d,
                              float* __restrict__ al_s, float* __restrict__ al_d,
                              int heads, int hd) {
  int idx = blockIdx.x * blockDim.x + threadIdx.x;
  if (idx >= N_NODES * heads) return;
  int n = idx / heads, hh = idx % heads;
  float ps = 0.f, pd = 0.f;
  for (int d = 0; d < DH; ++d) {
    float v = h[(size_t)n * hd + hh * DH + d];
    ps += v * a_s[hh * DH + d];
    pd += v * a_d[hh * DH + d];
  }
  al_s[idx] = ps;
  al_d[idx] = pd;
}

// ---- edge scores: leaky_relu(al_s[src] + al_d[dst])
__global__ void k_edge_scores(const int* __restrict__ ei,
                              const float* __restrict__ al_s,
                              const float* __restrict__ al_d,
                              float* __restrict__ sc, int heads) {
  int e = blockIdx.x * blockDim.x + threadIdx.x;
  if (e >= EP) return;
  int s = src_of(ei, e), d = dst_of(ei, e);
  for (int hh = 0; hh < heads; ++hh) {
    float v = al_s[s * heads + hh] + al_d[d * heads + hh];
    v = v > 0.f ? v : 0.2f * v;
    v = (v == v) ? v : 0.f;
    sc[(size_t)e * heads + hh] = v;
  }
}

// ---- CSR build (by dst): count / 3-stage wave scan / scatter  [validated R3==R5]
__global__ void k_count(const int* __restrict__ ei, int* __restrict__ counts) {
  int e = blockIdx.x * blockDim.x + threadIdx.x;
  if (e >= EP) return;
  atomicAdd(&counts[dst_of(ei, e)], 1);
}
__global__ void k_scan_a(const int* __restrict__ counts, int* __restrict__ part) {
  int lane = threadIdx.x;
  int i = blockIdx.x * 64 + lane;
  int v = (i < N_NODES) ? counts[i] : 0;
  v = wave_isum(v);
  if (lane == 0) part[blockIdx.x] = v;
}
__global__ void k_scan_b(const int* __restrict__ part, int* __restrict__ partpref) {
  int lane = threadIdx.x;
  int carry = 0;
  for (int base = 0; base < SCB; base += 64) {
    int i = base + lane;
    int v = (i < SCB) ? part[i] : 0;
    int inc = wave_iscan(v, lane);
    if (i < SCB) partpref[i] = carry + inc - v;
    carry += __shfl(inc, 63);
  }
  if (lane == 0) partpref[SCB] = carry;
}
__global__ void k_scan_c(const int* __restrict__ counts, const int* __restrict__ partpref,
                         int* __restrict__ row_ptr, int* __restrict__ cursor) {
  int b = blockIdx.x, lane = threadIdx.x;
  int i = b * 64 + lane;
  int v = (i < N_NODES) ? counts[i] : 0;
  int inc = wave_iscan(v, lane);
  int excl = partpref[b] + inc - v;
  if (i < N_NODES) { row_ptr[i] = excl; cursor[i] = excl; }
  if (i == N_NODES - 1) row_ptr[N_NODES] = excl + v;
}
__global__ void k_scatter(const int* __restrict__ ei, int* __restrict__ cursor,
                          int* __restrict__ eidx) {
  int e = blockIdx.x * blockDim.x + threadIdx.x;
  if (e >= EP) return;
  int pos = atomicAdd(&cursor[dst_of(ei, e)], 1);
  if ((unsigned)pos < EP) eidx[pos] = e;
}

// ---- per-(dst,head) wave: softmax over in-edges + weighted gather-sum + alpha store
__global__ void k_aggregate(const float* __restrict__ sc,
                            const int* __restrict__ eidx,
                            const int* __restrict__ row_ptr,
                            const int* __restrict__ ei,
                            const float* __restrict__ h,
                            float* __restrict__ out_acc,
                            float* __restrict__ att,
                            int heads, int hd) {
  int wid = blockIdx.x * (blockDim.x >> 6) + (threadIdx.x >> 6);
  if (wid >= N_NODES * heads) return;
  int lane = threadIdx.x & 63;
  int n = wid / heads, hh = wid % heads;
  int beg = row_ptr[n], end = row_ptr[n + 1];
  if (beg < 0) beg = 0;
  if (end > EP) end = EP;
  float m = -1e30f;
  for (int i = beg + lane; i < end; i += 64) {
    unsigned ue = (unsigned)eidx[i];
    int eid = (ue < EP) ? (int)ue : 0;
    m = fmaxf(m, sc[(size_t)eid * heads + hh]);
  }
  m = wave_max(m);
  float ssum = 0.f;
  for (int i = beg + lane; i < end; i += 64) {
    unsigned ue = (unsigned)eidx[i];
    int eid = (ue < EP) ? (int)ue : 0;
    ssum += __expf(sc[(size_t)eid * heads + hh] - m);
  }
  ssum = wave_sum(ssum);
  float inv = (ssum > 0.f) ? 1.f / ssum : 0.f;
  float acc = 0.f;
  for (int i = beg; i < end; ++i) {
    unsigned ue = (unsigned)eidx[i];
    int eid = (ue < EP) ? (int)ue : 0;
    float al = __expf(sc[(size_t)eid * heads + hh] - m) * inv;
    int s = src_of(ei, eid);
    acc += al * h[(size_t)s * hd + hh * DH + lane];
    if (lane == 0) att[(size_t)eid * heads + hh] = al;
  }
  out_acc[(size_t)n * hd + hh * DH + lane] = acc;
}

// ---- bias + ELU, in place (fp32)
__global__ void k_bias_elu(float* __restrict__ acc, const float* __restrict__ b,
                           int total, int hd) {
  int i = blockIdx.x * blockDim.x + threadIdx.x;
  if (i >= total) return;
  float v = acc[i] + b[i % hd];
  acc[i] = v > 0.f ? v : expm1f(v);
}

// ---- graph segment starts (batch is sorted)
__global__ void k_gstart(const int* __restrict__ batch, int* __restrict__ gstart) {
  int i = blockIdx.x * blockDim.x + threadIdx.x;
  if (i >= N_NODES) return;
  int g = batch[i] & (NG - 1);
  if (i == 0) gstart[g] = 0;
  else {
    int gp = batch[i - 1] & (NG - 1);
    if (g != gp) gstart[g] = i;
  }
}
__global__ void k_gfix(int* __restrict__ gstart) {
  if (threadIdx.x != 0 || blockIdx.x != 0) return;
  gstart[NG] = N_NODES;
  for (int g = NG - 1; g >= 0; --g)
    if (gstart[g] < 0) gstart[g] = gstart[g + 1];
}

// ---- deterministic pooling: one block per graph, zero atomics
__global__ __launch_bounds__(1024) void k_pool2(const float* __restrict__ acc,
                                                const float* __restrict__ b3,
                                                const int* __restrict__ gstart,
                                                float* __restrict__ pooled,
                                                float* __restrict__ cnt) {
  __shared__ float red[16][DH];
  int g = blockIdx.x;
  int lo = gstart[g], hi = gstart[g + 1];
  int d = threadIdx.x & (DH - 1);
  int sub = threadIdx.x >> 6;            // 0..15
  float s = 0.f;
  for (int n = lo + sub; n < hi; n += 16)
    s += acc[(size_t)n * DH + d];
  red[sub][d] = s;
  __syncthreads();
  if (sub == 0) {
    float tot = 0.f;
#pragma unroll
    for (int r = 0; r < 16; ++r) tot += red[r][d];
    int c = hi - lo;
    pooled[g * DH + d] = tot + (float)c * b3[d];
    if (d == 0) cnt[g] = (float)c;
  }
}

// ---- final tiny MLP (one block), fp32 logits
__global__ void k_mlp(const float* __restrict__ pooled, const float* __restrict__ cnt,
                      const float* __restrict__ Wc1, const float* __restrict__ bc1,
                      const float* __restrict__ Wc2, const float* __restrict__ bc2,
                      float* __restrict__ out) {
  __shared__ float hid[NG * 32];
  int t = threadIdx.x;
  for (int idx = t; idx < NG * 32; idx += blockDim.x) {
    int g = idx / 32, j = idx % 32;
    float invc = 1.f / fmaxf(cnt[g], 1.f);
    float a = bc1[j];
    for (int d = 0; d < DH; ++d)
      a += pooled[g * DH + d] * invc * Wc1[d * 32 + j];
    hid[idx] = a > 0.f ? a : 0.f;
  }
  __syncthreads();
  for (int idx = t; idx < NG * NC; idx += blockDim.x) {
    int g = idx / NC, c = idx % NC;
    float a = bc2[c];
    for (int j = 0; j < 32; ++j)
      a += hid[g * 32 + j] * Wc2[j * NC + c];
    out[idx] = a;
  }
}

extern "C" void kernel_launch(void* const* d_in, const int* in_sizes, int n_in,
                              void* d_out, int out_size, void* d_ws, size_t ws_size,
                              hipStream_t stream) {
  const float* x   = (const float*)d_in[0];
  const int* ei    = (const int*)d_in[1];     // (2,E) rows, int32
  const int* batch = (const int*)d_in[2];
  const float* W1  = (const float*)d_in[3];
  const float* as1 = (const float*)d_in[4];
  const float* ad1 = (const float*)d_in[5];
  const float* b1  = (const float*)d_in[6];
  const float* W2  = (const float*)d_in[7];
  const float* as2 = (const float*)d_in[8];
  const float* ad2 = (const float*)d_in[9];
  const float* b2  = (const float*)d_in[10];
  const float* W3  = (const float*)d_in[11];
  const float* as3 = (const float*)d_in[12];
  const float* ad3 = (const float*)d_in[13];
  const float* b3  = (const float*)d_in[14];
  const float* Wc1 = (const float*)d_in[15];
  const float* bc1 = (const float*)d_in[16];
  const float* Wc2 = (const float*)d_in[17];
  const float* bc2 = (const float*)d_in[18];
  float* out = (float*)d_out;                 // fp32 outputs

  // workspace carve (~122 MB)
  char* w = (char*)d_ws;
  float* h_f32   = (float*)(w + 0);            // 51,200,000
  float* out_acc = (float*)(w + 51200000);     // 51,200,000 (x2/x3 after in-place ELU)
  float* al_s    = (float*)(w + 102400000);    // 800,000
  float* al_d    = (float*)(w + 103200000);    // 800,000
  float* sc      = (float*)(w + 104000000);    // 13,600,000
  int*   counts  = (int*)(w + 117600000);      // 200,000
  int*   cursor  = (int*)(w + 117800000);      // 200,000
  int*   row_ptr = (int*)(w + 118000000);      // 200,004
  int*   eidx    = (int*)(w + 118200064);      // 3,400,000
  int*   part    = (int*)(w + 121600064);      // 3,200
  int*   partpref= (int*)(w + 121603264);      // 3,200
  float* pooled  = (float*)(w + 121606464);    // 8,192
  float* gcnt    = (float*)(w + 121614656);    // 128
  int*   gstart  = (int*)(w + 121614784);      // 132

  const int EB  = (EP + 255) / 256;
  const int NH4 = (N_NODES * 4 + 255) / 256;

  hipMemsetAsync(counts, 0, N_NODES * sizeof(int), stream);
  hipMemsetAsync(eidx, 0, EP * sizeof(int), stream);
  hipMemsetAsync(gstart, 0xFF, (NG + 1) * sizeof(int), stream);

  // ---- CSR build (shared by all 3 layers) + graph segment starts
  k_count<<<EB, 256, 0, stream>>>(ei, counts);
  k_scan_a<<<SCB, 64, 0, stream>>>(counts, part);
  k_scan_b<<<1, 64, 0, stream>>>(part, partpref);
  k_scan_c<<<SCB, 64, 0, stream>>>(counts, partpref, row_ptr, cursor);
  k_scatter<<<EB, 256, 0, stream>>>(ei, cursor, eidx);
  k_gstart<<<(N_NODES + 255) / 256, 256, 0, stream>>>(batch, gstart);
  k_gfix<<<1, 64, 0, stream>>>(gstart);

  float* att1 = out + 96;
  float* att2 = out + 3400096;
  float* att3 = out + 6800096;

  dim3 gh(HD / BN, (N_NODES + BM - 1) / BM);   // 4 x 782
  dim3 gd(DH / BN, (N_NODES + BM - 1) / BM);   // 1 x 782

  // ================= layer 1: x[N,128] @ W1[128,256] =================
  k_gemm<<<gh, 256, 0, stream>>>(x, W1, h_f32, N_NODES, HD, F_IN);
  k_node_scores<<<NH4, 256, 0, stream>>>(h_f32, as1, ad1, al_s, al_d, 4, HD);
  k_edge_scores<<<EB, 256, 0, stream>>>(ei, al_s, al_d, sc, 4);
  k_aggregate<<<N_NODES, 256, 0, stream>>>(sc, eidx, row_ptr, ei, h_f32,
                                           out_acc, att1, 4, HD);
  k_bias_elu<<<(N_NODES * HD + 255) / 256, 256, 0, stream>>>(out_acc, b1, N_NODES * HD, HD);

  // ================= layer 2: x2[N,256] @ W2[256,256] =================
  k_gemm<<<gh, 256, 0, stream>>>(out_acc, W2, h_f32, N_NODES, HD, HD);
  k_node_scores<<<NH4, 256, 0, stream>>>(h_f32, as2, ad2, al_s, al_d, 4, HD);
  k_edge_scores<<<EB, 256, 0, stream>>>(ei, al_s, al_d, sc, 4);
  k_aggregate<<<N_NODES, 256, 0, stream>>>(sc, eidx, row_ptr, ei, h_f32,
                                           out_acc, att2, 4, HD);
  k_bias_elu<<<(N_NODES * HD + 255) / 256, 256, 0, stream>>>(out_acc, b2, N_NODES * HD, HD);

  // ================= layer 3: x3[N,256] @ W3[256,64], heads=1 =================
  k_gemm<<<gd, 256, 0, stream>>>(out_acc, W3, h_f32, N_NODES, DH, HD);
  k_node_scores<<<(N_NODES + 255) / 256, 256, 0, stream>>>(h_f32, as3, ad3, al_s, al_d, 1, DH);
  k_edge_scores<<<EB, 256, 0, stream>>>(ei, al_s, al_d, sc, 1);
  k_aggregate<<<N_NODES / 4, 256, 0, stream>>>(sc, eidx, row_ptr, ei, h_f32,
                                               out_acc, att3, 1, DH);

  // ---- deterministic pooling + classifier head
  k_pool2<<<NG, 1024, 0, stream>>>(out_acc, b3, gstart, pooled, gcnt);
  k_mlp<<<1, 256, 0, stream>>>(pooled, gcnt, Wc1, bc1, Wc2, bc2, out);
}

// Round 13
// 1097.547 us; speedup vs baseline: 3.8704x; 1.5859x over previous
//
#include <hip/hip_runtime.h>
#include <hip/hip_bf16.h>

#define N_NODES 50000
#define N_EDGES 800000
#define EP (N_EDGES + N_NODES)   // 850000 edges incl. self-loops (appended at end)
#define F_IN 128
#define DH 64
#define HD 256                   // 4 heads * 64
#define NG 32
#define NC 3
#define SCB 782                  // ceil(N_NODES/64)

__device__ inline float wave_max(float v) {
#pragma unroll
  for (int o = 32; o > 0; o >>= 1) v = fmaxf(v, __shfl_xor(v, o));
  return v;
}
__device__ inline float wave_sum(float v) {
#pragma unroll
  for (int o = 32; o > 0; o >>= 1) v += __shfl_xor(v, o);
  return v;
}
__device__ inline int wave_isum(int v) {
#pragma unroll
  for (int o = 32; o > 0; o >>= 1) v += __shfl_xor(v, o);
  return v;
}
__device__ inline int wave_iscan(int v, int lane) {   // inclusive
#pragma unroll
  for (int o = 1; o < 64; o <<= 1) {
    int t = __shfl_up(v, o);
    if (lane >= o) v += t;
  }
  return v;
}

// EDGE BUFFER: (2,E) int32 rows. src=ei[e], dst=ei[E+e]; self-loops at e>=E.
__device__ inline int src_of(const int* __restrict__ ei, int e) {
  int s = (e < N_EDGES) ? ei[e] : (e - N_EDGES);
  if ((unsigned)s >= N_NODES) s = 0;
  return s;
}
__device__ inline int dst_of(const int* __restrict__ ei, int e) {
  int d = (e < N_EDGES) ? ei[N_EDGES + e] : (e - N_EDGES);
  if ((unsigned)d >= N_NODES) d = 0;
  return d;
}

// ---- tiled fp32 GEMM: C[M,Nn] = A[M,K] @ W[K,Nn]; 64x64 tile, 4x4 per thread
#define BM 64
#define BN 64
#define BK 32
__global__ __launch_bounds__(256) void k_gemm(const float* __restrict__ A,
                                              const float* __restrict__ W,
                                              float* __restrict__ C,
                                              int M, int Nn, int K) {
  __shared__ float As[BK][BM + 1];
  __shared__ float Ws[BK][BN + 1];
  int t = threadIdx.x;
  int bm0 = blockIdx.y * BM, bn0 = blockIdx.x * BN;
  int ar = t >> 2, ak = (t & 3) * 8;
  int wk = t >> 3, wc = (t & 7) * 8;
  int ty = t >> 4, tx = t & 15;
  float acc[4][4] = {{0.f}};
  for (int k0 = 0; k0 < K; k0 += BK) {
    int arow = bm0 + ar;
    if (arow < M) {
      const float* ap = A + (size_t)arow * K + k0 + ak;
      float4 a0 = *(const float4*)ap;
      float4 a1 = *(const float4*)(ap + 4);
      As[ak + 0][ar] = a0.x; As[ak + 1][ar] = a0.y;
      As[ak + 2][ar] = a0.z; As[ak + 3][ar] = a0.w;
      As[ak + 4][ar] = a1.x; As[ak + 5][ar] = a1.y;
      As[ak + 6][ar] = a1.z; As[ak + 7][ar] = a1.w;
    } else {
#pragma unroll
      for (int j = 0; j < 8; ++j) As[ak + j][ar] = 0.f;
    }
    {
      const float* wp = W + (size_t)(k0 + wk) * Nn + bn0 + wc;
      float4 w0 = *(const float4*)wp;
      float4 w1 = *(const float4*)(wp + 4);
      Ws[wk][wc + 0] = w0.x; Ws[wk][wc + 1] = w0.y;
      Ws[wk][wc + 2] = w0.z; Ws[wk][wc + 3] = w0.w;
      Ws[wk][wc + 4] = w1.x; Ws[wk][wc + 5] = w1.y;
      Ws[wk][wc + 6] = w1.z; Ws[wk][wc + 7] = w1.w;
    }
    __syncthreads();
#pragma unroll
    for (int kk = 0; kk < BK; ++kk) {
      float ra[4], rb[4];
#pragma unroll
      for (int i = 0; i < 4; ++i) ra[i] = As[kk][ty * 4 + i];
#pragma unroll
      for (int j = 0; j < 4; ++j) rb[j] = Ws[kk][tx * 4 + j];
#pragma unroll
      for (int i = 0; i < 4; ++i)
#pragma unroll
        for (int j = 0; j < 4; ++j) acc[i][j] += ra[i] * rb[j];
    }
    __syncthreads();
  }
#pragma unroll
  for (int i = 0; i < 4; ++i) {
    int row = bm0 + ty * 4 + i;
    if (row >= M) continue;
#pragma unroll
    for (int j = 0; j < 4; ++j)
      C[(size_t)row * Nn + bn0 + tx * 4 + j] = acc[i][j];
  }
}

// ---- per-(node,head) attention logits
__global__ void k_node_scores(const float* __restrict__ h,
                              const float* __restrict__ a_s,
                              const float* __restrict__ a_d,
                              float* __restrict__ al_s, float* __restrict__ al_d,
                              int heads, int hd) {
  int idx = blockIdx.x * blockDim.x + threadIdx.x;
  if (idx >= N_NODES * heads) return;
  int n = idx / heads, hh = idx % heads;
  float ps = 0.f, pd = 0.f;
  for (int d = 0; d < DH; ++d) {
    float v = h[(size_t)n * hd + hh * DH + d];
    ps += v * a_s[hh * DH + d];
    pd += v * a_d[hh * DH + d];
  }
  al_s[idx] = ps;
  al_d[idx] = pd;
}

// ---- edge scores H=4: leaky_relu(al_s[src] + al_d[dst]), float4
__global__ void k_edge_scores4(const int* __restrict__ ei,
                               const float* __restrict__ al_s,
                               const float* __restrict__ al_d,
                               float* __restrict__ sc) {
  int e = blockIdx.x * blockDim.x + threadIdx.x;
  if (e >= EP) return;
  int s = src_of(ei, e), d = dst_of(ei, e);
  float4 a = *(const float4*)(al_s + (size_t)s * 4);
  float4 b = *(const float4*)(al_d + (size_t)d * 4);
  float4 v;
  v.x = a.x + b.x; v.x = v.x > 0.f ? v.x : 0.2f * v.x; v.x = (v.x == v.x) ? v.x : 0.f;
  v.y = a.y + b.y; v.y = v.y > 0.f ? v.y : 0.2f * v.y; v.y = (v.y == v.y) ? v.y : 0.f;
  v.z = a.z + b.z; v.z = v.z > 0.f ? v.z : 0.2f * v.z; v.z = (v.z == v.z) ? v.z : 0.f;
  v.w = a.w + b.w; v.w = v.w > 0.f ? v.w : 0.2f * v.w; v.w = (v.w == v.w) ? v.w : 0.f;
  *(float4*)(sc + (size_t)e * 4) = v;
}

// ---- edge scores H=1
__global__ void k_edge_scores1(const int* __restrict__ ei,
                               const float* __restrict__ al_s,
                               const float* __restrict__ al_d,
                               float* __restrict__ sc) {
  int e = blockIdx.x * blockDim.x + threadIdx.x;
  if (e >= EP) return;
  int s = src_of(ei, e), d = dst_of(ei, e);
  float v = al_s[s] + al_d[d];
  v = v > 0.f ? v : 0.2f * v;
  v = (v == v) ? v : 0.f;
  sc[e] = v;
}

// ---- CSR build (by dst): count / 3-stage wave scan / scatter (+src cache)
__global__ void k_count(const int* __restrict__ ei, int* __restrict__ counts) {
  int e = blockIdx.x * blockDim.x + threadIdx.x;
  if (e >= EP) return;
  atomicAdd(&counts[dst_of(ei, e)], 1);
}
__global__ void k_scan_a(const int* __restrict__ counts, int* __restrict__ part) {
  int lane = threadIdx.x;
  int i = blockIdx.x * 64 + lane;
  int v = (i < N_NODES) ? counts[i] : 0;
  v = wave_isum(v);
  if (lane == 0) part[blockIdx.x] = v;
}
__global__ void k_scan_b(const int* __restrict__ part, int* __restrict__ partpref) {
  int lane = threadIdx.x;
  int carry = 0;
  for (int base = 0; base < SCB; base += 64) {
    int i = base + lane;
    int v = (i < SCB) ? part[i] : 0;
    int inc = wave_iscan(v, lane);
    if (i < SCB) partpref[i] = carry + inc - v;
    carry += __shfl(inc, 63);
  }
  if (lane == 0) partpref[SCB] = carry;
}
__global__ void k_scan_c(const int* __restrict__ counts, const int* __restrict__ partpref,
                         int* __restrict__ row_ptr, int* __restrict__ cursor) {
  int b = blockIdx.x, lane = threadIdx.x;
  int i = b * 64 + lane;
  int v = (i < N_NODES) ? counts[i] : 0;
  int inc = wave_iscan(v, lane);
  int excl = partpref[b] + inc - v;
  if (i < N_NODES) { row_ptr[i] = excl; cursor[i] = excl; }
  if (i == N_NODES - 1) row_ptr[N_NODES] = excl + v;
}
__global__ void k_scatter(const int* __restrict__ ei, int* __restrict__ cursor,
                          int* __restrict__ eidx, int* __restrict__ srcs) {
  int e = blockIdx.x * blockDim.x + threadIdx.x;
  if (e >= EP) return;
  int pos = atomicAdd(&cursor[dst_of(ei, e)], 1);
  if ((unsigned)pos < EP) { eidx[pos] = e; srcs[pos] = src_of(ei, e); }
}

// ---- 4-head fused aggregate: wave per dst; lane = features [4*lane, 4*lane+3]
// (all in head lane>>4). One float4 h load covers the full 1KB row per edge.
// Epilogue fuses bias + ELU (layers 1-2).
__global__ __launch_bounds__(256) void k_aggregate4(
    const float* __restrict__ sc, const int* __restrict__ eidx,
    const int* __restrict__ srcs, const int* __restrict__ row_ptr,
    const float* __restrict__ h, const float* __restrict__ bias,
    float* __restrict__ xout, float* __restrict__ att) {
  int n = blockIdx.x * (blockDim.x >> 6) + (threadIdx.x >> 6);
  if (n >= N_NODES) return;
  int lane = threadIdx.x & 63;
  int beg = row_ptr[n], end = row_ptr[n + 1];
  if (beg < 0) beg = 0;
  if (end > EP) end = EP;
  // pass 1: per-head max
  float m0 = -1e30f, m1 = -1e30f, m2 = -1e30f, m3 = -1e30f;
  for (int i = beg + lane; i < end; i += 64) {
    float4 s4 = *(const float4*)(sc + (size_t)eidx[i] * 4);
    m0 = fmaxf(m0, s4.x); m1 = fmaxf(m1, s4.y);
    m2 = fmaxf(m2, s4.z); m3 = fmaxf(m3, s4.w);
  }
  m0 = wave_max(m0); m1 = wave_max(m1); m2 = wave_max(m2); m3 = wave_max(m3);
  // pass 2: per-head sum of exp
  float s0 = 0.f, s1 = 0.f, s2 = 0.f, s3 = 0.f;
  for (int i = beg + lane; i < end; i += 64) {
    float4 s4 = *(const float4*)(sc + (size_t)eidx[i] * 4);
    s0 += __expf(s4.x - m0); s1 += __expf(s4.y - m1);
    s2 += __expf(s4.z - m2); s3 += __expf(s4.w - m3);
  }
  s0 = wave_sum(s0); s1 = wave_sum(s1); s2 = wave_sum(s2); s3 = wave_sum(s3);
  float i0 = s0 > 0.f ? 1.f / s0 : 0.f;
  float i1 = s1 > 0.f ? 1.f / s1 : 0.f;
  float i2 = s2 > 0.f ? 1.f / s2 : 0.f;
  float i3 = s3 > 0.f ? 1.f / s3 : 0.f;
  // pass 3: gather-accumulate (serial over edges; all heads at once)
  int hsel = lane >> 4;
  float4 acc = {0.f, 0.f, 0.f, 0.f};
  for (int i = beg; i < end; ++i) {
    int eid = eidx[i];
    int s = srcs[i];
    if ((unsigned)s >= N_NODES) s = 0;
    float4 s4 = *(const float4*)(sc + (size_t)eid * 4);
    float a0 = __expf(s4.x - m0) * i0;
    float a1 = __expf(s4.y - m1) * i1;
    float a2 = __expf(s4.z - m2) * i2;
    float a3 = __expf(s4.w - m3) * i3;
    float al = (hsel == 0) ? a0 : (hsel == 1) ? a1 : (hsel == 2) ? a2 : a3;
    float4 hv = *(const float4*)(h + (size_t)s * HD + lane * 4);
    acc.x += al * hv.x; acc.y += al * hv.y;
    acc.z += al * hv.z; acc.w += al * hv.w;
    if (lane == 0) {
      float4 av = {a0, a1, a2, a3};
      *(float4*)(att + (size_t)eid * 4) = av;
    }
  }
  // epilogue: bias + ELU, coalesced float4 store
  float4 b4 = *(const float4*)(bias + lane * 4);
  float4 o;
  o.x = acc.x + b4.x; o.x = o.x > 0.f ? o.x : expm1f(o.x);
  o.y = acc.y + b4.y; o.y = o.y > 0.f ? o.y : expm1f(o.y);
  o.z = acc.z + b4.z; o.z = o.z > 0.f ? o.z : expm1f(o.z);
  o.w = acc.w + b4.w; o.w = o.w > 0.f ? o.w : expm1f(o.w);
  *(float4*)(xout + (size_t)n * HD + lane * 4) = o;
}

// ---- H=1 aggregate (layer 3): wave per dst, lane = feature; no bias/ELU
__global__ __launch_bounds__(256) void k_aggregate1(
    const float* __restrict__ sc, const int* __restrict__ eidx,
    const int* __restrict__ srcs, const int* __restrict__ row_ptr,
    const float* __restrict__ h, float* __restrict__ out_acc,
    float* __restrict__ att) {
  int n = blockIdx.x * (blockDim.x >> 6) + (threadIdx.x >> 6);
  if (n >= N_NODES) return;
  int lane = threadIdx.x & 63;
  int beg = row_ptr[n], end = row_ptr[n + 1];
  if (beg < 0) beg = 0;
  if (end > EP) end = EP;
  float m = -1e30f;
  for (int i = beg + lane; i < end; i += 64)
    m = fmaxf(m, sc[eidx[i]]);
  m = wave_max(m);
  float ssum = 0.f;
  for (int i = beg + lane; i < end; i += 64)
    ssum += __expf(sc[eidx[i]] - m);
  ssum = wave_sum(ssum);
  float inv = (ssum > 0.f) ? 1.f / ssum : 0.f;
  float acc = 0.f;
  for (int i = beg; i < end; ++i) {
    int eid = eidx[i];
    int s = srcs[i];
    if ((unsigned)s >= N_NODES) s = 0;
    float al = __expf(sc[eid] - m) * inv;
    acc += al * h[(size_t)s * DH + lane];
    if (lane == 0) att[eid] = al;
  }
  out_acc[(size_t)n * DH + lane] = acc;
}

// ---- graph segment starts (batch is sorted)
__global__ void k_gstart(const int* __restrict__ batch, int* __restrict__ gstart) {
  int i = blockIdx.x * blockDim.x + threadIdx.x;
  if (i >= N_NODES) return;
  int g = batch[i] & (NG - 1);
  if (i == 0) gstart[g] = 0;
  else {
    int gp = batch[i - 1] & (NG - 1);
    if (g != gp) gstart[g] = i;
  }
}
__global__ void k_gfix(int* __restrict__ gstart) {
  if (threadIdx.x != 0 || blockIdx.x != 0) return;
  gstart[NG] = N_NODES;
  for (int g = NG - 1; g >= 0; --g)
    if (gstart[g] < 0) gstart[g] = gstart[g + 1];
}

// ---- deterministic pooling: one block per graph, zero atomics
__global__ __launch_bounds__(1024) void k_pool2(const float* __restrict__ acc,
                                                const float* __restrict__ b3,
                                                const int* __restrict__ gstart,
                                                float* __restrict__ pooled,
                                                float* __restrict__ cnt) {
  __shared__ float red[16][DH];
  int g = blockIdx.x;
  int lo = gstart[g], hi = gstart[g + 1];
  int d = threadIdx.x & (DH - 1);
  int sub = threadIdx.x >> 6;
  float s = 0.f;
  for (int n = lo + sub; n < hi; n += 16)
    s += acc[(size_t)n * DH + d];
  red[sub][d] = s;
  __syncthreads();
  if (sub == 0) {
    float tot = 0.f;
#pragma unroll
    for (int r = 0; r < 16; ++r) tot += red[r][d];
    int c = hi - lo;
    pooled[g * DH + d] = tot + (float)c * b3[d];
    if (d == 0) cnt[g] = (float)c;
  }
}

// ---- final tiny MLP (one block), fp32 logits
__global__ void k_mlp(const float* __restrict__ pooled, const float* __restrict__ cnt,
                      const float* __restrict__ Wc1, const float* __restrict__ bc1,
                      const float* __restrict__ Wc2, const float* __restrict__ bc2,
                      float* __restrict__ out) {
  __shared__ float hid[NG * 32];
  int t = threadIdx.x;
  for (int idx = t; idx < NG * 32; idx += blockDim.x) {
    int g = idx / 32, j = idx % 32;
    float invc = 1.f / fmaxf(cnt[g], 1.f);
    float a = bc1[j];
    for (int d = 0; d < DH; ++d)
      a += pooled[g * DH + d] * invc * Wc1[d * 32 + j];
    hid[idx] = a > 0.f ? a : 0.f;
  }
  __syncthreads();
  for (int idx = t; idx < NG * NC; idx += blockDim.x) {
    int g = idx / NC, c = idx % NC;
    float a = bc2[c];
    for (int j = 0; j < 32; ++j)
      a += hid[g * 32 + j] * Wc2[j * NC + c];
    out[idx] = a;
  }
}

extern "C" void kernel_launch(void* const* d_in, const int* in_sizes, int n_in,
                              void* d_out, int out_size, void* d_ws, size_t ws_size,
                              hipStream_t stream) {
  const float* x   = (const float*)d_in[0];
  const int* ei    = (const int*)d_in[1];     // (2,E) rows, int32
  const int* batch = (const int*)d_in[2];
  const float* W1  = (const float*)d_in[3];
  const float* as1 = (const float*)d_in[4];
  const float* ad1 = (const float*)d_in[5];
  const float* b1  = (const float*)d_in[6];
  const float* W2  = (const float*)d_in[7];
  const float* as2 = (const float*)d_in[8];
  const float* ad2 = (const float*)d_in[9];
  const float* b2  = (const float*)d_in[10];
  const float* W3  = (const float*)d_in[11];
  const float* as3 = (const float*)d_in[12];
  const float* ad3 = (const float*)d_in[13];
  const float* b3  = (const float*)d_in[14];
  const float* Wc1 = (const float*)d_in[15];
  const float* bc1 = (const float*)d_in[16];
  const float* Wc2 = (const float*)d_in[17];
  const float* bc2 = (const float*)d_in[18];
  float* out = (float*)d_out;                 // fp32 outputs

  // workspace carve (~126 MB)
  char* w = (char*)d_ws;
  float* h_f32   = (float*)(w + 0);            // 51,200,000
  float* out_acc = (float*)(w + 51200000);     // 51,200,000 (x2/x3)
  float* al_s    = (float*)(w + 102400000);    // 800,000
  float* al_d    = (float*)(w + 103200000);    // 800,000
  float* sc      = (float*)(w + 104000000);    // 13,600,000
  int*   counts  = (int*)(w + 117600000);      // 200,000
  int*   cursor  = (int*)(w + 117800000);      // 200,000
  int*   row_ptr = (int*)(w + 118000000);      // 200,004
  int*   eidx    = (int*)(w + 118200064);      // 3,400,000
  int*   srcs    = (int*)(w + 121600064);      // 3,400,000
  int*   part    = (int*)(w + 125000064);      // 3,200
  int*   partpref= (int*)(w + 125003264);      // 3,200
  float* pooled  = (float*)(w + 125006464);    // 8,192
  float* gcnt    = (float*)(w + 125014656);    // 128
  int*   gstart  = (int*)(w + 125014784);      // 132

  const int EB  = (EP + 255) / 256;
  const int NH4 = (N_NODES * 4 + 255) / 256;
  const int NB  = (N_NODES + 3) / 4;           // blocks of 4 waves, wave per node

  hipMemsetAsync(counts, 0, N_NODES * sizeof(int), stream);
  hipMemsetAsync(eidx, 0, EP * sizeof(int), stream);
  hipMemsetAsync(srcs, 0, EP * sizeof(int), stream);
  hipMemsetAsync(gstart, 0xFF, (NG + 1) * sizeof(int), stream);

  // ---- CSR build (shared by all 3 layers) + graph segment starts
  k_count<<<EB, 256, 0, stream>>>(ei, counts);
  k_scan_a<<<SCB, 64, 0, stream>>>(counts, part);
  k_scan_b<<<1, 64, 0, stream>>>(part, partpref);
  k_scan_c<<<SCB, 64, 0, stream>>>(counts, partpref, row_ptr, cursor);
  k_scatter<<<EB, 256, 0, stream>>>(ei, cursor, eidx, srcs);
  k_gstart<<<(N_NODES + 255) / 256, 256, 0, stream>>>(batch, gstart);
  k_gfix<<<1, 64, 0, stream>>>(gstart);

  float* att1 = out + 96;
  float* att2 = out + 3400096;
  float* att3 = out + 6800096;

  dim3 gh(HD / BN, (N_NODES + BM - 1) / BM);
  dim3 gd(DH / BN, (N_NODES + BM - 1) / BM);

  // ================= layer 1: x[N,128] @ W1[128,256] =================
  k_gemm<<<gh, 256, 0, stream>>>(x, W1, h_f32, N_NODES, HD, F_IN);
  k_node_scores<<<NH4, 256, 0, stream>>>(h_f32, as1, ad1, al_s, al_d, 4, HD);
  k_edge_scores4<<<EB, 256, 0, stream>>>(ei, al_s, al_d, sc);
  k_aggregate4<<<NB, 256, 0, stream>>>(sc, eidx, srcs, row_ptr, h_f32, b1,
                                       out_acc, att1);

  // ================= layer 2: x2[N,256] @ W2[256,256] =================
  k_gemm<<<gh, 256, 0, stream>>>(out_acc, W2, h_f32, N_NODES, HD, HD);
  k_node_scores<<<NH4, 256, 0, stream>>>(h_f32, as2, ad2, al_s, al_d, 4, HD);
  k_edge_scores4<<<EB, 256, 0, stream>>>(ei, al_s, al_d, sc);
  k_aggregate4<<<NB, 256, 0, stream>>>(sc, eidx, srcs, row_ptr, h_f32, b2,
                                       out_acc, att2);

  // ================= layer 3: x3[N,256] @ W3[256,64], heads=1 =================
  k_gemm<<<gd, 256, 0, stream>>>(out_acc, W3, h_f32, N_NODES, DH, HD);
  k_node_scores<<<(N_NODES + 255) / 256, 256, 0, stream>>>(h_f32, as3, ad3, al_s, al_d, 1, DH);
  k_edge_scores1<<<EB, 256, 0, stream>>>(ei, al_s, al_d, sc);
  k_aggregate1<<<NB, 256, 0, stream>>>(sc, eidx, srcs, row_ptr, h_f32,
                                       out_acc, att3);

  // ---- deterministic pooling + classifier head
  k_pool2<<<NG, 1024, 0, stream>>>(out_acc, b3, gstart, pooled, gcnt);
  k_mlp<<<1, 256, 0, stream>>>(pooled, gcnt, Wc1, bc1, Wc2, bc2, out);
}